// Round 9
// baseline (633.875 us; speedup 1.0000x reference)
//
#include <hip/hip_runtime.h>
#include <math.h>

#define N_NODES 16000
#define N_EDGES 256000
#define EPE (N_EDGES + N_NODES)
#define DIN 1280
#define HID 256
#define HEADS 8
#define CPH 32
#define NG 32
#define NO 64
#define EPSC 1e-5f
#define CAP 32      // src rows cached per chunk in gat_fused
#define XPAD 264    // xs row stride (bf16) in gat_fused
#define SPAD 40     // GEMM LDS row stride (bf16): 80 B, 16B-aligned

typedef __bf16 bf16;
typedef __attribute__((ext_vector_type(8))) __bf16 bf16x8;
typedef __attribute__((ext_vector_type(4))) float floatx4;

__device__ __forceinline__ float lrelu(float v) { return v > 0.f ? v : 0.2f * v; }
__device__ __forceinline__ float bflo(unsigned int u) { return __uint_as_float(u << 16); }
__device__ __forceinline__ float bfhi(unsigned int u) { return __uint_as_float(u & 0xffff0000u); }
__device__ __forceinline__ unsigned int bfpack(float x, float y) {
    bf16 b0 = (bf16)x, b1 = (bf16)y;
    return ((unsigned int)*(unsigned short*)&b0) | (((unsigned int)*(unsigned short*)&b1) << 16);
}

// ---------- ALL weight conversions in one kernel ----------
// segments: fpWt 327680 | wlrT0 131072 | wlrT1 131072 | gwT 131072 | rwT 131072 | pwT 65536
__global__ void wconv_all(const float* __restrict__ fp_W, const float* __restrict__ Wl,
                          const float* __restrict__ Wr, const float* __restrict__ gin_W,
                          const float* __restrict__ res_W, const float* __restrict__ pool_W1,
                          bf16* __restrict__ fpWt, bf16* __restrict__ wlrT0,
                          bf16* __restrict__ wlrT1, bf16* __restrict__ gwT,
                          bf16* __restrict__ rwT, bf16* __restrict__ pwT)
{
    int idx = blockIdx.x * 256 + threadIdx.x;
    if (idx < 327680) {
        int n = idx / DIN, k = idx - n * DIN;
        fpWt[idx] = (bf16)fp_W[(size_t)k * HID + n];
    } else if (idx < 327680 + 262144) {
        int r = idx - 327680;
        int layer = r >> 17, rr = r & 131071;
        int n = rr >> 8, k = rr & 255;
        const float* Ws = (n < 256) ? (Wl + layer * 65536) : (Wr + layer * 65536);
        bf16 v = (bf16)Ws[k * HID + (n & 255)];
        if (layer) wlrT1[rr] = v; else wlrT0[rr] = v;
    } else if (idx < 327680 + 262144 + 131072) {
        int r = idx - (327680 + 262144);
        int l = r >> 16, nk = r & 65535;
        int n = nk >> 8, k = nk & 255;
        gwT[r] = (bf16)gin_W[(l << 16) + (k << 8) + n];
    } else if (idx < 327680 + 262144 + 262144) {
        int r = idx - (327680 + 262144 + 131072);
        int l = r >> 16, nk = r & 65535;
        int n = nk >> 8, k = nk & 255;
        rwT[r] = (bf16)res_W[(l << 16) + (k << 8) + n];
    } else if (idx < 327680 + 262144 + 262144 + 65536) {
        int r = idx - (327680 + 262144 + 262144);
        int n = r >> 8, k = r & 255;
        pwT[r] = (bf16)pool_W1[(k << 8) + n];
    }
}

// ---------- MFMA GEMM 64x64 tile, single barrier/iter, reg prefetch ----------
__global__ __launch_bounds__(256) void gemm64(
    const bf16* __restrict__ A, const bf16* __restrict__ Bt,
    const float* __restrict__ bias, const float* __restrict__ bias2,
    bf16* __restrict__ C, int K, int ldc, int mode,
    const float* __restrict__ g, const float* __restrict__ be)
{
    __shared__ __align__(16) bf16 As[2][64 * SPAD];
    __shared__ __align__(16) bf16 Bs[2][64 * SPAD];
    const int tid = threadIdx.x;
    const int bm = blockIdx.y * 64, bn = blockIdx.x * 64;
    const int w = tid >> 6, lane = tid & 63;
    const int wm = w * 16;
    const int lrow = lane & 15, lk8 = (lane >> 4) * 8;
    const int row = tid >> 2, k8 = (tid & 3) * 8;

    const bf16* gA = A + (size_t)(bm + row) * K + k8;
    const bf16* gB = Bt + (size_t)(bn + row) * K + k8;

    floatx4 acc[4];
#pragma unroll
    for (int j = 0; j < 4; j++) acc[j] = (floatx4){0.f, 0.f, 0.f, 0.f};

    const int nk = K >> 5;
    bf16x8 ra = *(const bf16x8*)gA;
    bf16x8 rb = *(const bf16x8*)gB;

    for (int it = 0; it < nk; ++it) {
        int p = it & 1;
        *(bf16x8*)&As[p][row * SPAD + k8] = ra;
        *(bf16x8*)&Bs[p][row * SPAD + k8] = rb;
        __syncthreads();
        if (it + 1 < nk) {
            ra = *(const bf16x8*)(gA + (it + 1) * 32);
            rb = *(const bf16x8*)(gB + (it + 1) * 32);
        }
        bf16x8 af = *(const bf16x8*)&As[p][(wm + lrow) * SPAD + lk8];
        bf16x8 bfr[4];
#pragma unroll
        for (int j = 0; j < 4; j++) bfr[j] = *(const bf16x8*)&Bs[p][(16 * j + lrow) * SPAD + lk8];
#pragma unroll
        for (int j = 0; j < 4; j++)
            acc[j] = __builtin_amdgcn_mfma_f32_16x16x32_bf16(af, bfr[j], acc[j], 0, 0, 0);
    }

    const float inv = rsqrtf(1.f + EPSC);
    const int row0 = bm + wm + (lane >> 4) * 4;
#pragma unroll
    for (int j = 0; j < 4; j++) {
        int col = bn + 16 * j + lrow;
        float bcol = (col < HID) ? bias[col] : bias2[col - HID];
        float gc = (mode >= 1) ? g[col] * inv : 0.f;
        float bec = (mode >= 1) ? be[col] : 0.f;
#pragma unroll
        for (int r = 0; r < 4; r++) {
            float z = acc[j][r] + bcol;
            if (mode >= 1) { z = fmaxf(z, 0.f); z = z * gc + bec; }
            if (mode == 2) z = lrelu(z);
            C[(size_t)(row0 + r) * ldc + col] = (bf16)z;
        }
    }
}

// ---------- MFMA GEMM (fp32 A), 128x128 tile, 4-deep register pipeline ----------
__global__ __launch_bounds__(256, 1) void gemm_f32A(
    const float* __restrict__ A, const bf16* __restrict__ Bt,
    const float* __restrict__ bias, bf16* __restrict__ C, int K,
    const float* __restrict__ g, const float* __restrict__ be)
{
    __shared__ __align__(16) bf16 As[2][128 * SPAD];
    __shared__ __align__(16) bf16 Bs[2][128 * SPAD];
    const int tid = threadIdx.x;
    const int bm = blockIdx.y * 128, bn = blockIdx.x * 128;
    const int w = tid >> 6, lane = tid & 63;
    const int wm = (w & 1) * 64, wn = (w >> 1) * 64;
    const int lrow = lane & 15, lk8 = (lane >> 4) * 8;

    floatx4 acc[4][4];
#pragma unroll
    for (int i = 0; i < 4; i++)
#pragma unroll
        for (int j = 0; j < 4; j++) acc[i][j] = (floatx4){0.f, 0.f, 0.f, 0.f};

    const int r2 = tid >> 1, c2 = tid & 1;
    const float* gA = A + (size_t)(bm + r2) * K + c2 * 16;
    const bf16* gB = Bt + (size_t)(bn + r2) * K + c2 * 16;
    bf16* sA = &As[0][r2 * SPAD + c2 * 16];
    bf16* sB = &Bs[0][r2 * SPAD + c2 * 16];

    const int nk = K >> 5;   // 40
    float4 a[4][4];
    bf16x8 b[4][2];
#pragma unroll
    for (int u = 0; u < 4; u++) {
        const float* pa = gA + u * 32;
        a[u][0] = *(const float4*)(pa + 0);
        a[u][1] = *(const float4*)(pa + 4);
        a[u][2] = *(const float4*)(pa + 8);
        a[u][3] = *(const float4*)(pa + 12);
        const bf16* pb = gB + u * 32;
        b[u][0] = *(const bf16x8*)(pb + 0);
        b[u][1] = *(const bf16x8*)(pb + 8);
    }

    for (int it0 = 0; it0 < nk; it0 += 4) {
#pragma unroll
        for (int u = 0; u < 4; u++) {
            const int it = it0 + u;
            const int p = u & 1;
            const int po = p * 128 * SPAD;
            bf16x8 h0, h1;
            h0[0] = (bf16)a[u][0].x; h0[1] = (bf16)a[u][0].y; h0[2] = (bf16)a[u][0].z; h0[3] = (bf16)a[u][0].w;
            h0[4] = (bf16)a[u][1].x; h0[5] = (bf16)a[u][1].y; h0[6] = (bf16)a[u][1].z; h0[7] = (bf16)a[u][1].w;
            h1[0] = (bf16)a[u][2].x; h1[1] = (bf16)a[u][2].y; h1[2] = (bf16)a[u][2].z; h1[3] = (bf16)a[u][2].w;
            h1[4] = (bf16)a[u][3].x; h1[5] = (bf16)a[u][3].y; h1[6] = (bf16)a[u][3].z; h1[7] = (bf16)a[u][3].w;
            *(bf16x8*)(sA + po + 0) = h0;
            *(bf16x8*)(sA + po + 8) = h1;
            *(bf16x8*)(sB + po + 0) = b[u][0];
            *(bf16x8*)(sB + po + 8) = b[u][1];
            __syncthreads();
            if (it + 4 < nk) {
                const float* pa = gA + (it + 4) * 32;
                a[u][0] = *(const float4*)(pa + 0);
                a[u][1] = *(const float4*)(pa + 4);
                a[u][2] = *(const float4*)(pa + 8);
                a[u][3] = *(const float4*)(pa + 12);
                const bf16* pb = gB + (it + 4) * 32;
                b[u][0] = *(const bf16x8*)(pb + 0);
                b[u][1] = *(const bf16x8*)(pb + 8);
            }
            bf16x8 af[4], bfr[4];
#pragma unroll
            for (int i = 0; i < 4; i++) af[i] = *(const bf16x8*)&As[p][(wm + 16 * i + lrow) * SPAD + lk8];
#pragma unroll
            for (int j = 0; j < 4; j++) bfr[j] = *(const bf16x8*)&Bs[p][(wn + 16 * j + lrow) * SPAD + lk8];
#pragma unroll
            for (int i = 0; i < 4; i++)
#pragma unroll
                for (int j = 0; j < 4; j++)
                    acc[i][j] = __builtin_amdgcn_mfma_f32_16x16x32_bf16(af[i], bfr[j], acc[i][j], 0, 0, 0);
        }
    }

    const float inv = rsqrtf(1.f + EPSC);
#pragma unroll
    for (int j = 0; j < 4; j++) {
        int col = bn + wn + 16 * j + lrow;
        float bcol = bias[col];
        float gc = g[col] * inv;
        float bec = be[col];
#pragma unroll
        for (int i = 0; i < 4; i++) {
            int row0 = bm + wm + 16 * i + (lane >> 4) * 4;
#pragma unroll
            for (int r = 0; r < 4; r++) {
                float z = fmaxf(acc[i][j][r] + bcol, 0.f) * gc + bec;
                C[(size_t)(row0 + r) * HID + col] = (bf16)z;
            }
        }
    }
}

// ---------- CSR build ----------
__global__ void hist_kernel(const int* __restrict__ ei, int* __restrict__ cnt) {
    int e = blockIdx.x * 256 + threadIdx.x;
    if (e >= EPE) return;
    int d = (e < N_EDGES) ? ei[N_EDGES + e] : (e - N_EDGES);
    atomicAdd(&cnt[d], 1);
}

// prefix scan over node degrees + graph boundary binary search (fused)
__global__ __launch_bounds__(1024) void scan_kernel(const int* __restrict__ cnt,
                                                    int* __restrict__ roff, int* __restrict__ cursor,
                                                    const int* __restrict__ batch,
                                                    int* __restrict__ gstart) {
    __shared__ int wsum[16];
    int t = threadIdx.x;
    int base = t * 16;
    int local[16]; int s = 0;
#pragma unroll
    for (int i = 0; i < 16; i++) {
        int idx = base + i;
        int v = (idx < N_NODES) ? cnt[idx] : 0;
        local[i] = s; s += v;
    }
    int lane = t & 63, wid = t >> 6;
    int incl = s;
    for (int o = 1; o < 64; o <<= 1) { int v = __shfl_up(incl, o); if (lane >= o) incl += v; }
    if (lane == 63) wsum[wid] = incl;
    __syncthreads();
    if (t == 0) { int a = 0; for (int k = 0; k < 16; k++) { int v = wsum[k]; wsum[k] = a; a += v; } }
    __syncthreads();
    int texcl = incl - s + wsum[wid];
#pragma unroll
    for (int i = 0; i < 16; i++) {
        int idx = base + i;
        if (idx < N_NODES) { int o = texcl + local[i]; roff[idx] = o; cursor[idx] = o; }
    }
    if (t == 1023) roff[N_NODES] = texcl + s;
    if (t <= NG) {
        int lo = 0, hi = N_NODES;
        while (lo < hi) { int mid = (lo + hi) >> 1; if (batch[mid] < t) lo = mid + 1; else hi = mid; }
        gstart[t] = lo;
    }
}

__global__ void scatter_kernel(const int* __restrict__ ei, int* __restrict__ cursor,
                               int* __restrict__ esrc) {
    int e = blockIdx.x * 256 + threadIdx.x;
    if (e >= EPE) return;
    int s, d;
    if (e < N_EDGES) { s = ei[e]; d = ei[N_EDGES + e]; }
    else { s = d = e - N_EDGES; }
    int pos = atomicAdd(&cursor[d], 1);
    esrc[pos] = s;
}

// ---------- fused GATv2: parallel logits + online softmax + split packed accumulation ----------
__global__ __launch_bounds__(256) void gat_fused(
    const bf16* __restrict__ XLR, const int* __restrict__ roff, const int* __restrict__ esrc,
    const float* __restrict__ att, const float* __restrict__ gbias, bf16* __restrict__ out)
{
    const int d = blockIdx.x, t = threadIdx.x;
    const int beg = roff[d], deg = roff[d + 1] - beg;
    __shared__ __align__(16) bf16 xs[CAP][XPAD];
    __shared__ __align__(16) float4 xa4[8 * 16];
    __shared__ float llog[CAP * 8];
    __shared__ float comb[256];
    __shared__ float m_s[8], s_s[8], resc[8];

    if (t < 128) {
        int hh = t >> 4, cc = t & 15;
        int c = hh * 32 + cc * 2;
        float xr0 = (float)XLR[(size_t)d * 512 + 256 + c];
        float xr1 = (float)XLR[(size_t)d * 512 + 256 + c + 1];
        xa4[hh * 16 + cc] = (float4){xr0, att[c], xr1, att[c + 1]};
    }
    if (t < 8) { m_s[t] = -INFINITY; s_s[t] = 0.f; }

    const int jj = t & 31;          // logit: edge slot
    const int hh = t >> 5;          // logit: head
    const int sg = t >> 5, sl = t & 31;   // staging groups
    const int half = t >> 7;        // accum: even/odd edges
    const int tc = t & 127;         // accum: channel pair
    const int ch0 = tc * 2;         // channels ch0, ch0+1 (same head)
    const int ha = tc >> 4;         // head of ch0
    float a0 = 0.f, a1 = 0.f;

    for (int c0 = 0; c0 < deg; c0 += CAP) {
        int cn = min(CAP, deg - c0);
        __syncthreads();
        for (int r = sg; r < cn; r += 8) {
            int s = esrc[beg + c0 + r];
            *(bf16x8*)(&xs[r][sl * 8]) = *(const bf16x8*)(XLR + (size_t)s * 512 + sl * 8);
        }
        __syncthreads();
        if (jj < cn) {
            float lg = 0.f;
#pragma unroll
            for (int cc = 0; cc < 16; cc++) {
                int ce = (cc + jj) & 15;
                unsigned int p = *(const unsigned int*)&xs[jj][hh * 32 + ce * 2];
                float4 xa = xa4[hh * 16 + ce];
                lg += lrelu(bflo(p) + xa.x) * xa.y + lrelu(bfhi(p) + xa.z) * xa.w;
            }
            llog[jj * 8 + hh] = lg;
        }
        __syncthreads();
        if (t < 64) {
            int h2 = t & 7, j0 = t >> 3;
            float mx = -INFINITY;
            for (int j = j0; j < cn; j += 8) mx = fmaxf(mx, llog[j * 8 + h2]);
            for (int o = 8; o < 64; o <<= 1) mx = fmaxf(mx, __shfl_xor(mx, o));
            float mo = m_s[h2];
            float mn = fmaxf(mo, mx);
            float ss = 0.f;
            for (int j = j0; j < cn; j += 8) {
                float e = __expf(llog[j * 8 + h2] - mn);
                llog[j * 8 + h2] = e;
                ss += e;
            }
            for (int o = 8; o < 64; o <<= 1) ss += __shfl_xor(ss, o);
            if (t < 8) {
                float r = __expf(mo - mn);
                resc[h2] = r;
                s_s[h2] = s_s[h2] * r + ss;
                m_s[h2] = mn;
            }
        }
        __syncthreads();
        float rs = resc[ha];
        a0 *= rs; a1 *= rs;
        for (int j = half; j < cn; j += 2) {
            float wgt = llog[j * 8 + ha];
            unsigned int p = *(const unsigned int*)&xs[j][ch0];
            a0 = fmaf(wgt, bflo(p), a0);
            a1 = fmaf(wgt, bfhi(p), a1);
        }
    }
    __syncthreads();
    if (half) { comb[ch0] = a0; comb[ch0 + 1] = a1; }
    __syncthreads();
    if (!half) {
        float r = 1.f / (s_s[ha] + 1e-16f);
        float v0 = gbias[ch0] + (a0 + comb[ch0]) * r;
        float v1 = gbias[ch0 + 1] + (a1 + comb[ch0 + 1]) * r;
        *(unsigned int*)(out + (size_t)d * HID + ch0) = bfpack(v0, v1);
    }
}

// ---------- GIN gather: u[d] = sum over ALL CSR entries of h[src] ----------
__global__ __launch_bounds__(256) void gin_gather(
    const unsigned int* __restrict__ hu, const int* __restrict__ roff,
    const int* __restrict__ esrc, unsigned int* __restrict__ uu)
{
    int d = blockIdx.x, t = threadIdx.x;
    int grp = t >> 7, c = t & 127;
    int beg = roff[d], end = roff[d + 1];
    float a0 = 0.f, a1 = 0.f;
    int p = beg + grp;
    while (p + 14 < end) {
        int s[8];
#pragma unroll
        for (int k = 0; k < 8; k++) s[k] = esrc[p + 2 * k];
        unsigned int v[8];
#pragma unroll
        for (int k = 0; k < 8; k++) v[k] = hu[(size_t)s[k] * 128 + c];
#pragma unroll
        for (int k = 0; k < 8; k++) { a0 += bflo(v[k]); a1 += bfhi(v[k]); }
        p += 16;
    }
    for (; p < end; p += 2) {
        unsigned int v = hu[(size_t)esrc[p] * 128 + c];
        a0 += bflo(v); a1 += bfhi(v);
    }
    __shared__ float plo[128], phi[128];
    if (grp) { plo[c] = a0; phi[c] = a1; }
    __syncthreads();
    if (!grp) {
        a0 += plo[c]; a1 += phi[c];
        uu[(size_t)d * 128 + c] = bfpack(a0, a1);
    }
}

// ---------- global LN ----------
__global__ void stats_kernel(const bf16* __restrict__ x, float2* __restrict__ part, int n8) {
    float s = 0.f, sq = 0.f;
    for (int i = blockIdx.x * blockDim.x + threadIdx.x; i < n8; i += gridDim.x * blockDim.x) {
        bf16x8 v = *(const bf16x8*)(x + (size_t)i * 8);
#pragma unroll
        for (int j = 0; j < 8; j++) { float f = (float)v[j]; s += f; sq += f * f; }
    }
    for (int o = 32; o > 0; o >>= 1) { s += __shfl_down(s, o); sq += __shfl_down(sq, o); }
    __shared__ float ls[4], lq[4];
    int wid = threadIdx.x >> 6, lane = threadIdx.x & 63;
    if (lane == 0) { ls[wid] = s; lq[wid] = sq; }
    __syncthreads();
    if (threadIdx.x == 0)
        part[blockIdx.x] = make_float2(ls[0] + ls[1] + ls[2] + ls[3],
                                       lq[0] + lq[1] + lq[2] + lq[3]);
}

__global__ void stats_reduce(const float2* __restrict__ part, float* __restrict__ stat) {
    int t = threadIdx.x;
    float2 v = part[t];
    float s = v.x, q = v.y;
    for (int o = 32; o > 0; o >>= 1) { s += __shfl_down(s, o); q += __shfl_down(q, o); }
    __shared__ float ls[4], lq[4];
    int wid = t >> 6, lane = t & 63;
    if (lane == 0) { ls[wid] = s; lq[wid] = q; }
    __syncthreads();
    if (t == 0) { stat[0] = ls[0] + ls[1] + ls[2] + ls[3]; stat[1] = lq[0] + lq[1] + lq[2] + lq[3]; }
}

__global__ void ln_res_kernel(const bf16* __restrict__ h, const bf16* __restrict__ r,
                              const float* __restrict__ stats, const float* __restrict__ g,
                              const float* __restrict__ b, bf16* __restrict__ out)
{
    int i = (blockIdx.x * 256 + threadIdx.x) * 4;
    const float inv_n = 1.f / (float)((size_t)N_NODES * HID);
    float mu = stats[0] * inv_n;
    float var = stats[1] * inv_n - mu * mu;
    float sd = sqrtf(fmaxf(var, 0.f));
    float rs = 1.f / (sd + EPSC);
    int ch = i & (HID - 1);
#pragma unroll
    for (int j = 0; j < 4; j++) {
        float v = ((float)h[i + j] - mu) * rs * g[ch + j] + b[ch + j] + (float)r[i + j];
        out[i + j] = (bf16)lrelu(v);
    }
}

// ---------- pooling ----------
__global__ __launch_bounds__(256) void pool_gate_kernel(const bf16* __restrict__ t,
    const float* __restrict__ W2, const float* __restrict__ b2, float* __restrict__ gate)
{
    int n = blockIdx.x * 4 + (threadIdx.x >> 6);
    int lane = threadIdx.x & 63;
    const bf16* p = t + (size_t)n * HID + lane * 4;
    float4 w = *(const float4*)(W2 + lane * 4);
    float s = tanhf((float)p[0]) * w.x + tanhf((float)p[1]) * w.y
            + tanhf((float)p[2]) * w.z + tanhf((float)p[3]) * w.w;
    for (int o = 32; o > 0; o >>= 1) s += __shfl_down(s, o);
    if (lane == 0) gate[n] = s + b2[0];
}

// one block per graph: softmax over segment + weighted channel accumulation (no atomics)
__global__ __launch_bounds__(256) void pool_emb_kernel(
    const float* __restrict__ gate, const int* __restrict__ gstart,
    const bf16* __restrict__ h, float* __restrict__ emb)
{
    int g = blockIdx.x, t = threadIdx.x;
    int lo = gstart[g], hi = gstart[g + 1];
    int cnt = hi - lo;
    __shared__ float red[256];
    __shared__ float alpha[1024];
    float m = -INFINITY;
    for (int n = lo + t; n < hi; n += 256) m = fmaxf(m, gate[n]);
    red[t] = m; __syncthreads();
    for (int st = 128; st > 0; st >>= 1) { if (t < st) red[t] = fmaxf(red[t], red[t + st]); __syncthreads(); }
    m = red[0]; __syncthreads();
    float s = 0.f;
    for (int n = lo + t; n < hi; n += 256) {
        float e = __expf(gate[n] - m);
        if (n - lo < 1024) alpha[n - lo] = e;
        s += e;
    }
    red[t] = s; __syncthreads();
    for (int st = 128; st > 0; st >>= 1) { if (t < st) red[t] += red[t + st]; __syncthreads(); }
    float sinv = 1.f / (red[0] + 1e-16f);
    float acc = 0.f;
    const bf16* hp = h + (size_t)lo * HID + t;
    for (int n = 0; n < cnt; n++) {
        float a = (n < 1024) ? alpha[n] : __expf(gate[lo + n] - m);
        acc += a * (float)hp[(size_t)n * HID];
    }
    emb[g * HID + t] = acc * sinv;
}

// ---------- label heads ----------
__global__ __launch_bounds__(256) void heads_kernel(
    const float* __restrict__ emb, const float* __restrict__ W1, const float* __restrict__ b1,
    const float* __restrict__ hg, const float* __restrict__ hbe, const float* __restrict__ W2,
    const float* __restrict__ b2, float* __restrict__ out)
{
    int o = blockIdx.x;
    int g0 = blockIdx.y * 4;
    int k = threadIdx.x;
    __shared__ float se[4][HID];
    __shared__ float red[256];
#pragma unroll
    for (int j = 0; j < 4; j++) se[j][k] = emb[(g0 + j) * HID + k];
    __syncthreads();
    const float* w1p = W1 + (size_t)o * HID * HID + k;
    float zb = b1[o * HID + k];
    float z0 = zb, z1 = zb, z2 = zb, z3 = zb;
#pragma unroll 8
    for (int d = 0; d < HID; d++) {
        float w = w1p[(size_t)d * HID];
        z0 = fmaf(se[0][d], w, z0);
        z1 = fmaf(se[1][d], w, z1);
        z2 = fmaf(se[2][d], w, z2);
        z3 = fmaf(se[3][d], w, z3);
    }
    const float gk = hg[o * HID + k] * rsqrtf(1.f + EPSC);
    const float bek = hbe[o * HID + k];
    const float w2 = W2[o * HID + k];
    const float b2o = b2[o];
    float zz[4] = {z0, z1, z2, z3};
#pragma unroll
    for (int j = 0; j < 4; j++) {
        float z = zz[j];
        float sil = z / (1.f + expf(-z));
        red[k] = (sil * gk + bek) * w2;
        __syncthreads();
        for (int st = 128; st > 0; st >>= 1) { if (k < st) red[k] += red[k + st]; __syncthreads(); }
        if (k == 0) out[(g0 + j) * NO + o] = red[0] + b2o;
        __syncthreads();
    }
}

extern "C" void kernel_launch(void* const* d_in, const int* in_sizes, int n_in,
                              void* d_out, int out_size, void* d_ws, size_t ws_size,
                              hipStream_t stream) {
    const float* x        = (const float*)d_in[0];
    const int*   ei       = (const int*)  d_in[1];
    const int*   batch    = (const int*)  d_in[2];
    const float* fp_W     = (const float*)d_in[3];
    const float* fp_b     = (const float*)d_in[4];
    const float* fp_g     = (const float*)d_in[5];
    const float* fp_be    = (const float*)d_in[6];
    const float* gat_Wl   = (const float*)d_in[7];
    const float* gat_bl   = (const float*)d_in[8];
    const float* gat_Wr   = (const float*)d_in[9];
    const float* gat_br   = (const float*)d_in[10];
    const float* gat_att  = (const float*)d_in[11];
    const float* gat_bias = (const float*)d_in[12];
    const float* gin_W    = (const float*)d_in[13];
    const float* gin_b    = (const float*)d_in[14];
    const float* gin_g    = (const float*)d_in[15];
    const float* gin_be   = (const float*)d_in[16];
    const float* ln_g     = (const float*)d_in[17];
    const float* ln_b     = (const float*)d_in[18];
    const float* res_W    = (const float*)d_in[19];
    const float* res_b    = (const float*)d_in[20];
    const float* pool_W1  = (const float*)d_in[21];
    const float* pool_b1  = (const float*)d_in[22];
    const float* pool_W2  = (const float*)d_in[23];
    const float* pool_b2  = (const float*)d_in[24];
    const float* head_W1  = (const float*)d_in[25];
    const float* head_b1  = (const float*)d_in[26];
    const float* head_g   = (const float*)d_in[27];
    const float* head_be  = (const float*)d_in[28];
    const float* head_W2  = (const float*)d_in[29];
    const float* head_b2  = (const float*)d_in[30];
    float* out = (float*)d_out;

    char* base = (char*)d_ws;
    size_t off = 0;
    auto alloc = [&](size_t bytes) -> char* {
        char* p = base + off; off += (bytes + 255) & ~(size_t)255; return p;
    };
    int*   esrc   = (int*)  alloc((size_t)EPE * 4);
    int*   cnt    = (int*)  alloc((size_t)N_NODES * 4);
    int*   roff   = (int*)  alloc((size_t)(N_NODES + 1) * 4);
    int*   cursor = (int*)  alloc((size_t)N_NODES * 4);
    float* gate   = (float*)alloc((size_t)N_NODES * 4);
    int*   gstart = (int*)  alloc((NG + 1) * 4);
    float* emb    = (float*)alloc(NG * HID * 4);
    float* stat   = (float*)alloc(8);
    float2* statp = (float2*)alloc(256 * 8);
    bf16*  Hb0    = (bf16*) alloc((size_t)N_NODES * HID * 2);
    bf16*  Hb1    = (bf16*) alloc((size_t)N_NODES * HID * 2);
    bf16*  XLR    = (bf16*) alloc((size_t)N_NODES * 512 * 2);
    bf16*  fpWt   = (bf16*) alloc((size_t)DIN * HID * 2);
    bf16*  wlrT0  = (bf16*) alloc((size_t)512 * HID * 2);
    bf16*  wlrT1  = (bf16*) alloc((size_t)512 * HID * 2);
    bf16*  gwT    = (bf16*) alloc((size_t)2 * HID * HID * 2);
    bf16*  rwT    = (bf16*) alloc((size_t)2 * HID * HID * 2);
    bf16*  pwT    = (bf16*) alloc((size_t)HID * HID * 2);
    bf16*  Ub     = XLR;
    bf16*  wlrT[2] = { wlrT0, wlrT1 };

    // ---- all weight conversions in one launch ----
    wconv_all<<<3584, 256, 0, stream>>>(fp_W, gat_Wl, gat_Wr, gin_W, res_W, pool_W1,
                                        fpWt, wlrT0, wlrT1, gwT, rwT, pwT);

    // ---- CSR build (+ graph boundaries fused into scan) ----
    hipMemsetAsync(cnt, 0, N_NODES * sizeof(int), stream);
    hist_kernel<<<(EPE + 255) / 256, 256, 0, stream>>>(ei, cnt);
    scan_kernel<<<1, 1024, 0, stream>>>(cnt, roff, cursor, batch, gstart);
    scatter_kernel<<<(EPE + 255) / 256, 256, 0, stream>>>(ei, cursor, esrc);

    // ---- feature projection ----
    dim3 gridF(2, 125);          // 128x128 tiles
    dim3 g64_256(4, 250);        // 64x64 tiles, 256 cols
    dim3 g64_512(8, 250);        // 64x64 tiles, 512 cols
    gemm_f32A<<<gridF, 256, 0, stream>>>(x, fpWt, fp_b, Hb0, DIN, fp_g, fp_be);

    for (int i = 0; i < 2; i++) {
        gemm64<<<g64_512, 256, 0, stream>>>(Hb0, wlrT[i], gat_bl + i * HID, gat_br + i * HID,
                                            XLR, HID, 512, 0, nullptr, nullptr);
        gat_fused<<<N_NODES, 256, 0, stream>>>(XLR, roff, esrc, gat_att + i * HEADS * CPH,
                                               gat_bias + i * HID, Hb1);
        gin_gather<<<N_NODES, 256, 0, stream>>>((const unsigned int*)Hb1, roff, esrc,
                                                (unsigned int*)Ub);
        gemm64<<<g64_256, 256, 0, stream>>>(Ub, gwT + (size_t)i * HID * HID, gin_b + i * HID,
                                            nullptr, Hb0, HID, HID, 2,
                                            gin_g + i * HID, gin_be + i * HID);
        stats_kernel<<<256, 256, 0, stream>>>(Hb0, statp, (N_NODES * HID) / 8);
        stats_reduce<<<1, 256, 0, stream>>>(statp, stat);
        gemm64<<<g64_256, 256, 0, stream>>>(Hb0, rwT + (size_t)i * HID * HID, res_b + i * HID,
                                            nullptr, Hb1, HID, HID, 0, nullptr, nullptr);
        ln_res_kernel<<<(N_NODES * HID) / 1024, 256, 0, stream>>>(Hb0, Hb1, stat,
                                                                  ln_g + i * HID, ln_b + i * HID, Hb0);
    }

    // ---- global attention pooling ----
    gemm64<<<g64_256, 256, 0, stream>>>(Hb0, pwT, pool_b1, nullptr, Hb1, HID, HID, 0, nullptr, nullptr);
    pool_gate_kernel<<<N_NODES / 4, 256, 0, stream>>>(Hb1, pool_W2, pool_b2, gate);
    pool_emb_kernel<<<NG, 256, 0, stream>>>(gate, gstart, Hb0, emb);

    // ---- label heads ----
    dim3 hgrid(NO, 8);
    heads_kernel<<<hgrid, 256, 0, stream>>>(emb, head_W1, head_b1, head_g, head_be,
                                            head_W2, head_b2, out);
}

// Round 10
// 593.840 us; speedup vs baseline: 1.0674x; 1.0674x over previous
//
#include <hip/hip_runtime.h>
#include <math.h>

#define N_NODES 16000
#define N_EDGES 256000
#define EPE (N_EDGES + N_NODES)
#define DIN 1280
#define HID 256
#define HEADS 8
#define CPH 32
#define NG 32
#define NO 64
#define EPSC 1e-5f
#define CAP 32      // src rows cached per chunk in gat_fused
#define XPAD 264    // xs row stride (bf16) in gat_fused
#define SPAD 40     // GEMM LDS row stride (bf16): 80 B, 16B-aligned

typedef __bf16 bf16;
typedef __attribute__((ext_vector_type(8))) __bf16 bf16x8;
typedef __attribute__((ext_vector_type(4))) float floatx4;

__device__ __forceinline__ float lrelu(float v) { return v > 0.f ? v : 0.2f * v; }
__device__ __forceinline__ float bflo(unsigned int u) { return __uint_as_float(u << 16); }
__device__ __forceinline__ float bfhi(unsigned int u) { return __uint_as_float(u & 0xffff0000u); }
__device__ __forceinline__ unsigned int bfpack(float x, float y) {
    bf16 b0 = (bf16)x, b1 = (bf16)y;
    return ((unsigned int)*(unsigned short*)&b0) | (((unsigned int)*(unsigned short*)&b1) << 16);
}

// ---------- weight transpose/convert (separate small kernels; run concurrently) ----------
__global__ void wconv_gen(const float* __restrict__ W, bf16* __restrict__ Wt, int K, int total) {
    int idx = blockIdx.x * 256 + threadIdx.x;
    if (idx >= total) return;
    int per = K * HID;
    int l = idx / per, rem = idx - l * per;
    int n = rem / K, k = rem - n * K;
    Wt[idx] = (bf16)W[(size_t)l * per + (size_t)k * HID + n];
}

__global__ void wconv_pair(const float* __restrict__ Wl, const float* __restrict__ Wr,
                           bf16* __restrict__ Wt) {
    int idx = blockIdx.x * 256 + threadIdx.x;
    int n = idx >> 8, k = idx & 255;
    float v = (n < 256) ? Wl[(size_t)k * HID + n] : Wr[(size_t)k * HID + (n - 256)];
    Wt[idx] = (bf16)v;
}

// ---------- MFMA GEMM 64x64 tile, single barrier/iter, fused epilogues ----------
// mode 0: +bias
// mode 2: +bias,relu,bn,leaky  AND block stats (sum, sumsq) -> statp[bid]
// mode 3: residual+LN: out = lrelu( (h-mu)*rs*g + b + (acc+bias) ), h reloaded from A
__global__ __launch_bounds__(256) void gemm64(
    const bf16* __restrict__ A, const bf16* __restrict__ Bt,
    const float* __restrict__ bias, const float* __restrict__ bias2,
    bf16* __restrict__ C, int K, int ldc, int mode,
    const float* __restrict__ g, const float* __restrict__ be,
    float2* __restrict__ statp, const float* __restrict__ stat)
{
    __shared__ __align__(16) bf16 As[2][64 * SPAD];
    __shared__ __align__(16) bf16 Bs[2][64 * SPAD];
    const int tid = threadIdx.x;
    const int bm = blockIdx.y * 64, bn = blockIdx.x * 64;
    const int w = tid >> 6, lane = tid & 63;
    const int wm = w * 16;
    const int lrow = lane & 15, lk8 = (lane >> 4) * 8;
    const int row = tid >> 2, k8 = (tid & 3) * 8;

    const bf16* gA = A + (size_t)(bm + row) * K + k8;
    const bf16* gB = Bt + (size_t)(bn + row) * K + k8;

    floatx4 acc[4];
#pragma unroll
    for (int j = 0; j < 4; j++) acc[j] = (floatx4){0.f, 0.f, 0.f, 0.f};

    const int nk = K >> 5;
    bf16x8 ra = *(const bf16x8*)gA;
    bf16x8 rb = *(const bf16x8*)gB;

    for (int it = 0; it < nk; ++it) {
        int p = it & 1;
        *(bf16x8*)&As[p][row * SPAD + k8] = ra;
        *(bf16x8*)&Bs[p][row * SPAD + k8] = rb;
        __syncthreads();
        if (it + 1 < nk) {
            ra = *(const bf16x8*)(gA + (it + 1) * 32);
            rb = *(const bf16x8*)(gB + (it + 1) * 32);
        }
        bf16x8 af = *(const bf16x8*)&As[p][(wm + lrow) * SPAD + lk8];
        bf16x8 bfr[4];
#pragma unroll
        for (int j = 0; j < 4; j++) bfr[j] = *(const bf16x8*)&Bs[p][(16 * j + lrow) * SPAD + lk8];
#pragma unroll
        for (int j = 0; j < 4; j++)
            acc[j] = __builtin_amdgcn_mfma_f32_16x16x32_bf16(af, bfr[j], acc[j], 0, 0, 0);
    }

    const float inv = rsqrtf(1.f + EPSC);
    const int row0 = bm + wm + (lane >> 4) * 4;
    float mu = 0.f, rs = 0.f;
    if (mode == 3) {
        const float inv_n = 1.f / (float)((size_t)N_NODES * HID);
        mu = stat[0] * inv_n;
        float var = stat[1] * inv_n - mu * mu;
        rs = 1.f / (sqrtf(fmaxf(var, 0.f)) + EPSC);
    }
    float sz = 0.f, sq = 0.f;
#pragma unroll
    for (int j = 0; j < 4; j++) {
        int col = bn + 16 * j + lrow;
        float bcol = (col < HID) ? bias[col] : bias2[col - HID];
        float gc = (mode >= 2) ? g[col] : 0.f;
        float bec = (mode >= 2) ? be[col] : 0.f;
#pragma unroll
        for (int r = 0; r < 4; r++) {
            float z = acc[j][r] + bcol;
            if (mode == 2) {
                z = fmaxf(z, 0.f) * (gc * inv) + bec;
                z = lrelu(z);
                sz += z; sq += z * z;
            } else if (mode == 3) {
                float h = (float)A[(size_t)(row0 + r) * K + col];
                z = (h - mu) * rs * gc + bec + z;
                z = lrelu(z);
            }
            C[(size_t)(row0 + r) * ldc + col] = (bf16)z;
        }
    }
    if (mode == 2) {
        for (int o = 32; o > 0; o >>= 1) { sz += __shfl_down(sz, o); sq += __shfl_down(sq, o); }
        __syncthreads();                     // mainloop LDS readers done
        float* rs_ = (float*)&As[0][0];
        float* rq_ = (float*)&Bs[0][0];
        if (lane == 0) { rs_[w] = sz; rq_[w] = sq; }
        __syncthreads();
        if (tid == 0)
            statp[blockIdx.y * gridDim.x + blockIdx.x] =
                make_float2(rs_[0] + rs_[1] + rs_[2] + rs_[3],
                            rq_[0] + rq_[1] + rq_[2] + rq_[3]);
    }
}

// ---------- MFMA GEMM (fp32 A), 128x128 tile, 4-deep register pipeline ----------
__global__ __launch_bounds__(256, 1) void gemm_f32A(
    const float* __restrict__ A, const bf16* __restrict__ Bt,
    const float* __restrict__ bias, bf16* __restrict__ C, int K,
    const float* __restrict__ g, const float* __restrict__ be)
{
    __shared__ __align__(16) bf16 As[2][128 * SPAD];
    __shared__ __align__(16) bf16 Bs[2][128 * SPAD];
    const int tid = threadIdx.x;
    const int bm = blockIdx.y * 128, bn = blockIdx.x * 128;
    const int w = tid >> 6, lane = tid & 63;
    const int wm = (w & 1) * 64, wn = (w >> 1) * 64;
    const int lrow = lane & 15, lk8 = (lane >> 4) * 8;

    floatx4 acc[4][4];
#pragma unroll
    for (int i = 0; i < 4; i++)
#pragma unroll
        for (int j = 0; j < 4; j++) acc[i][j] = (floatx4){0.f, 0.f, 0.f, 0.f};

    const int r2 = tid >> 1, c2 = tid & 1;
    const float* gA = A + (size_t)(bm + r2) * K + c2 * 16;
    const bf16* gB = Bt + (size_t)(bn + r2) * K + c2 * 16;
    bf16* sA = &As[0][r2 * SPAD + c2 * 16];
    bf16* sB = &Bs[0][r2 * SPAD + c2 * 16];

    const int nk = K >> 5;   // 40
    float4 a[4][4];
    bf16x8 b[4][2];
#pragma unroll
    for (int u = 0; u < 4; u++) {
        const float* pa = gA + u * 32;
        a[u][0] = *(const float4*)(pa + 0);
        a[u][1] = *(const float4*)(pa + 4);
        a[u][2] = *(const float4*)(pa + 8);
        a[u][3] = *(const float4*)(pa + 12);
        const bf16* pb = gB + u * 32;
        b[u][0] = *(const bf16x8*)(pb + 0);
        b[u][1] = *(const bf16x8*)(pb + 8);
    }

    for (int it0 = 0; it0 < nk; it0 += 4) {
#pragma unroll
        for (int u = 0; u < 4; u++) {
            const int it = it0 + u;
            const int p = u & 1;
            const int po = p * 128 * SPAD;
            bf16x8 h0, h1;
            h0[0] = (bf16)a[u][0].x; h0[1] = (bf16)a[u][0].y; h0[2] = (bf16)a[u][0].z; h0[3] = (bf16)a[u][0].w;
            h0[4] = (bf16)a[u][1].x; h0[5] = (bf16)a[u][1].y; h0[6] = (bf16)a[u][1].z; h0[7] = (bf16)a[u][1].w;
            h1[0] = (bf16)a[u][2].x; h1[1] = (bf16)a[u][2].y; h1[2] = (bf16)a[u][2].z; h1[3] = (bf16)a[u][2].w;
            h1[4] = (bf16)a[u][3].x; h1[5] = (bf16)a[u][3].y; h1[6] = (bf16)a[u][3].z; h1[7] = (bf16)a[u][3].w;
            *(bf16x8*)(sA + po + 0) = h0;
            *(bf16x8*)(sA + po + 8) = h1;
            *(bf16x8*)(sB + po + 0) = b[u][0];
            *(bf16x8*)(sB + po + 8) = b[u][1];
            __syncthreads();
            if (it + 4 < nk) {
                const float* pa = gA + (it + 4) * 32;
                a[u][0] = *(const float4*)(pa + 0);
                a[u][1] = *(const float4*)(pa + 4);
                a[u][2] = *(const float4*)(pa + 8);
                a[u][3] = *(const float4*)(pa + 12);
                const bf16* pb = gB + (it + 4) * 32;
                b[u][0] = *(const bf16x8*)(pb + 0);
                b[u][1] = *(const bf16x8*)(pb + 8);
            }
            bf16x8 af[4], bfr[4];
#pragma unroll
            for (int i = 0; i < 4; i++) af[i] = *(const bf16x8*)&As[p][(wm + 16 * i + lrow) * SPAD + lk8];
#pragma unroll
            for (int j = 0; j < 4; j++) bfr[j] = *(const bf16x8*)&Bs[p][(wn + 16 * j + lrow) * SPAD + lk8];
#pragma unroll
            for (int i = 0; i < 4; i++)
#pragma unroll
                for (int j = 0; j < 4; j++)
                    acc[i][j] = __builtin_amdgcn_mfma_f32_16x16x32_bf16(af[i], bfr[j], acc[i][j], 0, 0, 0);
        }
    }

    const float inv = rsqrtf(1.f + EPSC);
#pragma unroll
    for (int j = 0; j < 4; j++) {
        int col = bn + wn + 16 * j + lrow;
        float bcol = bias[col];
        float gc = g[col] * inv;
        float bec = be[col];
#pragma unroll
        for (int i = 0; i < 4; i++) {
            int row0 = bm + wm + 16 * i + (lane >> 4) * 4;
#pragma unroll
            for (int r = 0; r < 4; r++) {
                float z = fmaxf(acc[i][j][r] + bcol, 0.f) * gc + bec;
                C[(size_t)(row0 + r) * HID + col] = (bf16)z;
            }
        }
    }
}

// ---------- CSR build ----------
__global__ void hist_kernel(const int* __restrict__ ei, int* __restrict__ cnt) {
    int e = blockIdx.x * 256 + threadIdx.x;
    if (e >= EPE) return;
    int d = (e < N_EDGES) ? ei[N_EDGES + e] : (e - N_EDGES);
    atomicAdd(&cnt[d], 1);
}

__global__ __launch_bounds__(1024) void scan_kernel(const int* __restrict__ cnt,
                                                    int* __restrict__ roff, int* __restrict__ cursor,
                                                    const int* __restrict__ batch,
                                                    int* __restrict__ gstart) {
    __shared__ int wsum[16];
    int t = threadIdx.x;
    int base = t * 16;
    int local[16]; int s = 0;
#pragma unroll
    for (int i = 0; i < 16; i++) {
        int idx = base + i;
        int v = (idx < N_NODES) ? cnt[idx] : 0;
        local[i] = s; s += v;
    }
    int lane = t & 63, wid = t >> 6;
    int incl = s;
    for (int o = 1; o < 64; o <<= 1) { int v = __shfl_up(incl, o); if (lane >= o) incl += v; }
    if (lane == 63) wsum[wid] = incl;
    __syncthreads();
    if (t == 0) { int a = 0; for (int k = 0; k < 16; k++) { int v = wsum[k]; wsum[k] = a; a += v; } }
    __syncthreads();
    int texcl = incl - s + wsum[wid];
#pragma unroll
    for (int i = 0; i < 16; i++) {
        int idx = base + i;
        if (idx < N_NODES) { int o = texcl + local[i]; roff[idx] = o; cursor[idx] = o; }
    }
    if (t == 1023) roff[N_NODES] = texcl + s;
    if (t <= NG) {
        int lo = 0, hi = N_NODES;
        while (lo < hi) { int mid = (lo + hi) >> 1; if (batch[mid] < t) lo = mid + 1; else hi = mid; }
        gstart[t] = lo;
    }
}

__global__ void scatter_kernel(const int* __restrict__ ei, int* __restrict__ cursor,
                               int* __restrict__ esrc) {
    int e = blockIdx.x * 256 + threadIdx.x;
    if (e >= EPE) return;
    int s, d;
    if (e < N_EDGES) { s = ei[e]; d = ei[N_EDGES + e]; }
    else { s = d = e - N_EDGES; }
    int pos = atomicAdd(&cursor[d], 1);
    esrc[pos] = s;
}

// ---------- fused GATv2: parallel logits + online softmax + split packed accumulation ----------
__global__ __launch_bounds__(256) void gat_fused(
    const bf16* __restrict__ XLR, const int* __restrict__ roff, const int* __restrict__ esrc,
    const float* __restrict__ att, const float* __restrict__ gbias, bf16* __restrict__ out)
{
    const int d = blockIdx.x, t = threadIdx.x;
    const int beg = roff[d], deg = roff[d + 1] - beg;
    __shared__ __align__(16) bf16 xs[CAP][XPAD];
    __shared__ __align__(16) float4 xa4[8 * 16];
    __shared__ float llog[CAP * 8];
    __shared__ float comb[256];
    __shared__ float m_s[8], s_s[8], resc[8];

    if (t < 128) {
        int hh = t >> 4, cc = t & 15;
        int c = hh * 32 + cc * 2;
        float xr0 = (float)XLR[(size_t)d * 512 + 256 + c];
        float xr1 = (float)XLR[(size_t)d * 512 + 256 + c + 1];
        xa4[hh * 16 + cc] = (float4){xr0, att[c], xr1, att[c + 1]};
    }
    if (t < 8) { m_s[t] = -INFINITY; s_s[t] = 0.f; }

    const int jj = t & 31;
    const int hh = t >> 5;
    const int sg = t >> 5, sl = t & 31;
    const int half = t >> 7;
    const int tc = t & 127;
    const int ch0 = tc * 2;
    const int ha = tc >> 4;
    float a0 = 0.f, a1 = 0.f;

    for (int c0 = 0; c0 < deg; c0 += CAP) {
        int cn = min(CAP, deg - c0);
        __syncthreads();
        for (int r = sg; r < cn; r += 8) {
            int s = esrc[beg + c0 + r];
            *(bf16x8*)(&xs[r][sl * 8]) = *(const bf16x8*)(XLR + (size_t)s * 512 + sl * 8);
        }
        __syncthreads();
        if (jj < cn) {
            float lg = 0.f;
#pragma unroll
            for (int cc = 0; cc < 16; cc++) {
                int ce = (cc + jj) & 15;
                unsigned int p = *(const unsigned int*)&xs[jj][hh * 32 + ce * 2];
                float4 xa = xa4[hh * 16 + ce];
                lg += lrelu(bflo(p) + xa.x) * xa.y + lrelu(bfhi(p) + xa.z) * xa.w;
            }
            llog[jj * 8 + hh] = lg;
        }
        __syncthreads();
        if (t < 64) {
            int h2 = t & 7, j0 = t >> 3;
            float mx = -INFINITY;
            for (int j = j0; j < cn; j += 8) mx = fmaxf(mx, llog[j * 8 + h2]);
            for (int o = 8; o < 64; o <<= 1) mx = fmaxf(mx, __shfl_xor(mx, o));
            float mo = m_s[h2];
            float mn = fmaxf(mo, mx);
            float ss = 0.f;
            for (int j = j0; j < cn; j += 8) {
                float e = __expf(llog[j * 8 + h2] - mn);
                llog[j * 8 + h2] = e;
                ss += e;
            }
            for (int o = 8; o < 64; o <<= 1) ss += __shfl_xor(ss, o);
            if (t < 8) {
                float r = __expf(mo - mn);
                resc[h2] = r;
                s_s[h2] = s_s[h2] * r + ss;
                m_s[h2] = mn;
            }
        }
        __syncthreads();
        float rsf = resc[ha];
        a0 *= rsf; a1 *= rsf;
        for (int j = half; j < cn; j += 2) {
            float wgt = llog[j * 8 + ha];
            unsigned int p = *(const unsigned int*)&xs[j][ch0];
            a0 = fmaf(wgt, bflo(p), a0);
            a1 = fmaf(wgt, bfhi(p), a1);
        }
    }
    __syncthreads();
    if (half) { comb[ch0] = a0; comb[ch0 + 1] = a1; }
    __syncthreads();
    if (!half) {
        float r = 1.f / (s_s[ha] + 1e-16f);
        float v0 = gbias[ch0] + (a0 + comb[ch0]) * r;
        float v1 = gbias[ch0 + 1] + (a1 + comb[ch0 + 1]) * r;
        *(unsigned int*)(out + (size_t)d * HID + ch0) = bfpack(v0, v1);
    }
}

// ---------- GIN gather: u[d] = sum over ALL CSR entries of h[src] ----------
__global__ __launch_bounds__(256) void gin_gather(
    const unsigned int* __restrict__ hu, const int* __restrict__ roff,
    const int* __restrict__ esrc, unsigned int* __restrict__ uu)
{
    int d = blockIdx.x, t = threadIdx.x;
    int grp = t >> 7, c = t & 127;
    int beg = roff[d], end = roff[d + 1];
    float a0 = 0.f, a1 = 0.f;
    int p = beg + grp;
    while (p + 14 < end) {
        int s[8];
#pragma unroll
        for (int k = 0; k < 8; k++) s[k] = esrc[p + 2 * k];
        unsigned int v[8];
#pragma unroll
        for (int k = 0; k < 8; k++) v[k] = hu[(size_t)s[k] * 128 + c];
#pragma unroll
        for (int k = 0; k < 8; k++) { a0 += bflo(v[k]); a1 += bfhi(v[k]); }
        p += 16;
    }
    for (; p < end; p += 2) {
        unsigned int v = hu[(size_t)esrc[p] * 128 + c];
        a0 += bflo(v); a1 += bfhi(v);
    }
    __shared__ float plo[128], phi[128];
    if (grp) { plo[c] = a0; phi[c] = a1; }
    __syncthreads();
    if (!grp) {
        a0 += plo[c]; a1 += phi[c];
        uu[(size_t)d * 128 + c] = bfpack(a0, a1);
    }
}

// ---------- stats reduce over per-block partials ----------
__global__ void stats_reduce(const float2* __restrict__ part, float* __restrict__ stat, int n) {
    int t = threadIdx.x;
    float s = 0.f, q = 0.f;
    for (int i = t; i < n; i += 256) { float2 v = part[i]; s += v.x; q += v.y; }
    for (int o = 32; o > 0; o >>= 1) { s += __shfl_down(s, o); q += __shfl_down(q, o); }
    __shared__ float ls[4], lq[4];
    int wid = t >> 6, lane = t & 63;
    if (lane == 0) { ls[wid] = s; lq[wid] = q; }
    __syncthreads();
    if (t == 0) { stat[0] = ls[0] + ls[1] + ls[2] + ls[3]; stat[1] = lq[0] + lq[1] + lq[2] + lq[3]; }
}

// ---------- pooling (R8 structure) ----------
__global__ __launch_bounds__(256) void pool_gate_kernel(const bf16* __restrict__ t,
    const float* __restrict__ W2, const float* __restrict__ b2, float* __restrict__ gate)
{
    int n = blockIdx.x * 4 + (threadIdx.x >> 6);
    int lane = threadIdx.x & 63;
    const bf16* p = t + (size_t)n * HID + lane * 4;
    float4 w = *(const float4*)(W2 + lane * 4);
    float s = tanhf((float)p[0]) * w.x + tanhf((float)p[1]) * w.y
            + tanhf((float)p[2]) * w.z + tanhf((float)p[3]) * w.w;
    for (int o = 32; o > 0; o >>= 1) s += __shfl_down(s, o);
    if (lane == 0) gate[n] = s + b2[0];
}

__global__ __launch_bounds__(256) void pool_stats_kernel(
    float* __restrict__ gate, const int* __restrict__ gstart)
{
    int g = blockIdx.x, t = threadIdx.x;
    int lo = gstart[g], hi = gstart[g + 1];
    __shared__ float red[256];
    float m = -INFINITY;
    for (int n = lo + t; n < hi; n += 256) m = fmaxf(m, gate[n]);
    red[t] = m; __syncthreads();
    for (int st = 128; st > 0; st >>= 1) { if (t < st) red[t] = fmaxf(red[t], red[t + st]); __syncthreads(); }
    m = red[0]; __syncthreads();
    float s = 0.f;
    for (int n = lo + t; n < hi; n += 256) s += __expf(gate[n] - m);
    red[t] = s; __syncthreads();
    for (int st = 128; st > 0; st >>= 1) { if (t < st) red[t] += red[t + st]; __syncthreads(); }
    float sinv = 1.f / (red[0] + 1e-16f);
    for (int n = lo + t; n < hi; n += 256) gate[n] = __expf(gate[n] - m) * sinv;
}

__global__ __launch_bounds__(256) void emb_accum_kernel(
    const float* __restrict__ a, const int* __restrict__ batch,
    const bf16* __restrict__ h, float* __restrict__ emb)
{
    int n0 = blockIdx.x * 32, t = threadIdx.x;
    int cur = batch[n0]; float acc = 0.f;
    for (int j = 0; j < 32; j++) {
        int n = n0 + j;
        int b = batch[n];
        if (b != cur) { atomicAdd(&emb[cur * HID + t], acc); cur = b; acc = 0.f; }
        acc += a[n] * (float)h[(size_t)n * HID + t];
    }
    atomicAdd(&emb[cur * HID + t], acc);
}

// ---------- label heads ----------
__global__ __launch_bounds__(256) void heads_kernel(
    const float* __restrict__ emb, const float* __restrict__ W1, const float* __restrict__ b1,
    const float* __restrict__ hg, const float* __restrict__ hbe, const float* __restrict__ W2,
    const float* __restrict__ b2, float* __restrict__ out)
{
    int o = blockIdx.x;
    int g0 = blockIdx.y * 4;
    int k = threadIdx.x;
    __shared__ float se[4][HID];
    __shared__ float red[256];
#pragma unroll
    for (int j = 0; j < 4; j++) se[j][k] = emb[(g0 + j) * HID + k];
    __syncthreads();
    const float* w1p = W1 + (size_t)o * HID * HID + k;
    float zb = b1[o * HID + k];
    float z0 = zb, z1 = zb, z2 = zb, z3 = zb;
#pragma unroll 8
    for (int d = 0; d < HID; d++) {
        float w = w1p[(size_t)d * HID];
        z0 = fmaf(se[0][d], w, z0);
        z1 = fmaf(se[1][d], w, z1);
        z2 = fmaf(se[2][d], w, z2);
        z3 = fmaf(se[3][d], w, z3);
    }
    const float gk = hg[o * HID + k] * rsqrtf(1.f + EPSC);
    const float bek = hbe[o * HID + k];
    const float w2 = W2[o * HID + k];
    const float b2o = b2[o];
    float zz[4] = {z0, z1, z2, z3};
#pragma unroll
    for (int j = 0; j < 4; j++) {
        float z = zz[j];
        float sil = z / (1.f + expf(-z));
        red[k] = (sil * gk + bek) * w2;
        __syncthreads();
        for (int st = 128; st > 0; st >>= 1) { if (k < st) red[k] += red[k + st]; __syncthreads(); }
        if (k == 0) out[(g0 + j) * NO + o] = red[0] + b2o;
        __syncthreads();
    }
}

extern "C" void kernel_launch(void* const* d_in, const int* in_sizes, int n_in,
                              void* d_out, int out_size, void* d_ws, size_t ws_size,
                              hipStream_t stream) {
    const float* x        = (const float*)d_in[0];
    const int*   ei       = (const int*)  d_in[1];
    const int*   batch    = (const int*)  d_in[2];
    const float* fp_W     = (const float*)d_in[3];
    const float* fp_b     = (const float*)d_in[4];
    const float* fp_g     = (const float*)d_in[5];
    const float* fp_be    = (const float*)d_in[6];
    const float* gat_Wl   = (const float*)d_in[7];
    const float* gat_bl   = (const float*)d_in[8];
    const float* gat_Wr   = (const float*)d_in[9];
    const float* gat_br   = (const float*)d_in[10];
    const float* gat_att  = (const float*)d_in[11];
    const float* gat_bias = (const float*)d_in[12];
    const float* gin_W    = (const float*)d_in[13];
    const float* gin_b    = (const float*)d_in[14];
    const float* gin_g    = (const float*)d_in[15];
    const float* gin_be   = (const float*)d_in[16];
    const float* ln_g     = (const float*)d_in[17];
    const float* ln_b     = (const float*)d_in[18];
    const float* res_W    = (const float*)d_in[19];
    const float* res_b    = (const float*)d_in[20];
    const float* pool_W1  = (const float*)d_in[21];
    const float* pool_b1  = (const float*)d_in[22];
    const float* pool_W2  = (const float*)d_in[23];
    const float* pool_b2  = (const float*)d_in[24];
    const float* head_W1  = (const float*)d_in[25];
    const float* head_b1  = (const float*)d_in[26];
    const float* head_g   = (const float*)d_in[27];
    const float* head_be  = (const float*)d_in[28];
    const float* head_W2  = (const float*)d_in[29];
    const float* head_b2  = (const float*)d_in[30];
    float* out = (float*)d_out;

    char* base = (char*)d_ws;
    size_t off = 0;
    auto alloc = [&](size_t bytes) -> char* {
        char* p = base + off; off += (bytes + 255) & ~(size_t)255; return p;
    };
    int*   esrc   = (int*)  alloc((size_t)EPE * 4);
    int*   cnt    = (int*)  alloc((size_t)N_NODES * 4);
    int*   roff   = (int*)  alloc((size_t)(N_NODES + 1) * 4);
    int*   cursor = (int*)  alloc((size_t)N_NODES * 4);
    float* gate   = (float*)alloc((size_t)N_NODES * 4);
    int*   gstart = (int*)  alloc((NG + 1) * 4);
    float* emb    = (float*)alloc(NG * HID * 4);
    float* stat   = (float*)alloc(8);
    float2* statp = (float2*)alloc(1024 * 8);
    bf16*  Hb0    = (bf16*) alloc((size_t)N_NODES * HID * 2);
    bf16*  Hb1    = (bf16*) alloc((size_t)N_NODES * HID * 2);
    bf16*  XLR    = (bf16*) alloc((size_t)N_NODES * 512 * 2);
    bf16*  fpWt   = (bf16*) alloc((size_t)DIN * HID * 2);
    bf16*  wlrT0  = (bf16*) alloc((size_t)512 * HID * 2);
    bf16*  wlrT1  = (bf16*) alloc((size_t)512 * HID * 2);
    bf16*  gwT    = (bf16*) alloc((size_t)2 * HID * HID * 2);
    bf16*  rwT    = (bf16*) alloc((size_t)2 * HID * HID * 2);
    bf16*  pwT    = (bf16*) alloc((size_t)HID * HID * 2);
    bf16*  Ub     = XLR;
    bf16*  wlrT[2] = { wlrT0, wlrT1 };

    // ---- weight conversions (small concurrent kernels) ----
    wconv_gen<<<(DIN * HID + 255) / 256, 256, 0, stream>>>(fp_W, fpWt, DIN, DIN * HID);
    wconv_pair<<<512, 256, 0, stream>>>(gat_Wl, gat_Wr, wlrT0);
    wconv_pair<<<512, 256, 0, stream>>>(gat_Wl + HID * HID, gat_Wr + HID * HID, wlrT1);
    wconv_gen<<<512, 256, 0, stream>>>(gin_W, gwT, HID, 2 * HID * HID);
    wconv_gen<<<512, 256, 0, stream>>>(res_W, rwT, HID, 2 * HID * HID);
    wconv_gen<<<256, 256, 0, stream>>>(pool_W1, pwT, HID, HID * HID);

    // ---- CSR build (+ graph boundaries fused into scan) ----
    hipMemsetAsync(cnt, 0, N_NODES * sizeof(int), stream);
    hist_kernel<<<(EPE + 255) / 256, 256, 0, stream>>>(ei, cnt);
    scan_kernel<<<1, 1024, 0, stream>>>(cnt, roff, cursor, batch, gstart);
    scatter_kernel<<<(EPE + 255) / 256, 256, 0, stream>>>(ei, cursor, esrc);

    // ---- feature projection ----
    dim3 gridF(2, 125);          // 128x128 tiles
    dim3 g64_256(4, 250);        // 64x64 tiles, 256 cols
    dim3 g64_512(8, 250);        // 64x64 tiles, 512 cols
    gemm_f32A<<<gridF, 256, 0, stream>>>(x, fpWt, fp_b, Hb0, DIN, fp_g, fp_be);

    bf16* hcur = Hb0;
    bf16* hoth = Hb1;
    for (int i = 0; i < 2; i++) {
        // xl|xr
        gemm64<<<g64_512, 256, 0, stream>>>(hcur, wlrT[i], gat_bl + i * HID, gat_br + i * HID,
                                            XLR, HID, 512, 0, nullptr, nullptr, nullptr, nullptr);
        // GAT -> hoth
        gat_fused<<<N_NODES, 256, 0, stream>>>(XLR, roff, esrc, gat_att + i * HEADS * CPH,
                                               gat_bias + i * HID, hoth);
        // GIN aggregate -> Ub
        gin_gather<<<N_NODES, 256, 0, stream>>>((const unsigned int*)hoth, roff, esrc,
                                                (unsigned int*)Ub);
        // h_gin = leaky(BN(relu(u@W+b))) -> hcur, + per-block LN stats
        gemm64<<<g64_256, 256, 0, stream>>>(Ub, gwT + (size_t)i * HID * HID, gin_b + i * HID,
                                            nullptr, hcur, HID, HID, 2,
                                            gin_g + i * HID, gin_be + i * HID, statp, nullptr);
        stats_reduce<<<1, 256, 0, stream>>>(statp, stat, 1000);
        // h = leaky(LN(h_gin) + h_gin@res_W + res_b) -> hoth (fused LN+residual epilogue)
        gemm64<<<g64_256, 256, 0, stream>>>(hcur, rwT + (size_t)i * HID * HID, res_b + i * HID,
                                            nullptr, hoth, HID, HID, 3,
                                            ln_g + i * HID, ln_b + i * HID, nullptr, stat);
        bf16* tmp = hcur; hcur = hoth; hoth = tmp;
    }

    // ---- global attention pooling (R8 structure) ----
    gemm64<<<g64_256, 256, 0, stream>>>(hcur, pwT, pool_b1, nullptr, hoth, HID, HID, 0,
                                        nullptr, nullptr, nullptr, nullptr);
    pool_gate_kernel<<<N_NODES / 4, 256, 0, stream>>>(hoth, pool_W2, pool_b2, gate);
    pool_stats_kernel<<<NG, 256, 0, stream>>>(gate, gstart);
    hipMemsetAsync(emb, 0, NG * HID * sizeof(float), stream);
    emb_accum_kernel<<<N_NODES / 32, 256, 0, stream>>>(gate, batch, hcur, emb);

    // ---- label heads ----
    dim3 hgrid(NO, 8);
    heads_kernel<<<hgrid, 256, 0, stream>>>(emb, head_W1, head_b1, head_g, head_be,
                                            head_W2, head_b2, out);
}